// Round 1
// baseline (2505.100 us; speedup 1.0000x reference)
//
#include <hip/hip_runtime.h>
#include <hip/hip_bf16.h>
#include <math.h>

#define B_    8
#define Nn    4096
#define Cc    320
#define NHEAD 8
#define CH    40
// scale = 40^-0.5
#define ATT_SCALE 0.15811388300841897f

// ---------------- CPE: depthwise 3x3 conv + bias + residual ----------------
// grid (B*N), block 320 (one thread per channel)
__global__ void cpe_kernel(const float* __restrict__ x, const float* __restrict__ w,
                           const float* __restrict__ bias, float* __restrict__ x1) {
    int bn = blockIdx.x;
    int c  = threadIdx.x;
    int b  = bn >> 12;
    int n  = bn & 4095;
    int y  = n >> 6, xx = n & 63;
    const float* xb = x + (size_t)b * Nn * Cc;
    float acc = bias[c];
    #pragma unroll
    for (int dy = -1; dy <= 1; ++dy) {
        int yy = y + dy;
        if ((unsigned)yy >= 64u) continue;
        #pragma unroll
        for (int dx = -1; dx <= 1; ++dx) {
            int x2 = xx + dx;
            if ((unsigned)x2 >= 64u) continue;
            acc += xb[(size_t)((yy << 6) + x2) * Cc + c] * w[c * 9 + (dy + 1) * 3 + (dx + 1)];
        }
    }
    float ctr = xb[(size_t)n * Cc + c];
    x1[(size_t)bn * Cc + c] = acc + ctr;
}

// ---------------- LayerNorm over C=320, one wave per token ----------------
__global__ void ln_kernel(const float* __restrict__ x, const float* __restrict__ g,
                          const float* __restrict__ bt, float* __restrict__ out) {
    int bn = blockIdx.x;
    int lane = threadIdx.x;
    const float* row = x + (size_t)bn * Cc;
    float v[5];
    float s = 0.f, s2 = 0.f;
    #pragma unroll
    for (int i = 0; i < 5; ++i) {
        v[i] = row[lane + 64 * i];
        s += v[i];
        s2 += v[i] * v[i];
    }
    #pragma unroll
    for (int off = 32; off > 0; off >>= 1) {
        s  += __shfl_down(s, off);
        s2 += __shfl_down(s2, off);
    }
    s  = __shfl(s, 0);
    s2 = __shfl(s2, 0);
    float mean = s * (1.f / 320.f);
    float var  = s2 * (1.f / 320.f) - mean * mean;
    float rstd = rsqrtf(var + 1e-6f);
    float* orow = out + (size_t)bn * Cc;
    #pragma unroll
    for (int i = 0; i < 5; ++i) {
        int c = lane + 64 * i;
        orow[c] = (v[i] - mean) * rstd * g[c] + bt[c];
    }
}

// ---------------- fp32 tiled GEMM: out = A(MxK) @ W(NxK)^T + bias (+res)(+gelu) ----------------
// 64x64 tile, BK=16, 256 threads, 4x4 per thread. All dims divide exactly.
template <int ACT>
__global__ __launch_bounds__(256) void gemm_kernel(
        const float* __restrict__ A, const float* __restrict__ Wt,
        const float* __restrict__ bias, const float* __restrict__ res,
        float* __restrict__ out, int M, int Kd, int Nout) {
    __shared__ float As[16][65];
    __shared__ float Bs[16][65];
    int tid = threadIdx.x;
    int m0 = blockIdx.x * 64;
    int n0 = blockIdx.y * 64;
    int tx = tid & 15, ty = tid >> 4;
    float acc[4][4] = {};
    for (int k0 = 0; k0 < Kd; k0 += 16) {
        #pragma unroll
        for (int i = 0; i < 4; ++i) {
            int l = tid + 256 * i;
            int m = l >> 4, k = l & 15;
            As[k][m] = A[(size_t)(m0 + m) * Kd + k0 + k];
            Bs[k][m] = Wt[(size_t)(n0 + m) * Kd + k0 + k];
        }
        __syncthreads();
        #pragma unroll
        for (int kk = 0; kk < 16; ++kk) {
            float a[4], bb[4];
            #pragma unroll
            for (int i = 0; i < 4; ++i) a[i]  = As[kk][ty * 4 + i];
            #pragma unroll
            for (int j = 0; j < 4; ++j) bb[j] = Bs[kk][tx * 4 + j];
            #pragma unroll
            for (int i = 0; i < 4; ++i)
                #pragma unroll
                for (int j = 0; j < 4; ++j)
                    acc[i][j] += a[i] * bb[j];
        }
        __syncthreads();
    }
    #pragma unroll
    for (int i = 0; i < 4; ++i) {
        int m = m0 + ty * 4 + i;
        #pragma unroll
        for (int j = 0; j < 4; ++j) {
            int n = n0 + tx * 4 + j;
            float v = acc[i][j] + bias[n];
            if (res) v += res[(size_t)m * Nout + n];
            if (ACT == 1) v = 0.5f * v * (1.f + erff(v * 0.70710678118654752f));
            out[(size_t)m * Nout + n] = v;
        }
    }
}

// ---------------- K softmax over tokens: partial online (max,sum) ----------------
// grid: (b,h,s) = 512 blocks, block 320: ch = tid%40, seg = tid/40
__global__ void ksm_partial(const float* __restrict__ qkv, float* __restrict__ pm,
                            float* __restrict__ ps) {
    int blk = blockIdx.x;
    int s = blk & 7;
    int bh = blk >> 3;
    int h = bh & 7, b = bh >> 3;
    int tid = threadIdx.x;
    int ch = tid % 40, seg = tid / 40;
    const float* base = qkv + (size_t)b * Nn * 960 + 320 + h * 40 + ch;
    float m = -1e30f, sum = 0.f;
    int n0 = s * 512;
    for (int i = 0; i < 64; ++i) {
        int n = n0 + seg + i * 8;
        float kx = base[(size_t)n * 960];
        float mn = fmaxf(m, kx);
        sum = sum * __expf(m - mn) + __expf(kx - mn);
        m = mn;
    }
    __shared__ float sm[8][40], ss[8][40];
    sm[seg][ch] = m;
    ss[seg][ch] = sum;
    __syncthreads();
    if (tid < 40) {
        float M = -1e30f;
        for (int g2 = 0; g2 < 8; ++g2) M = fmaxf(M, sm[g2][tid]);
        float S = 0.f;
        for (int g2 = 0; g2 < 8; ++g2) S += ss[g2][tid] * __expf(sm[g2][tid] - M);
        pm[blk * 40 + tid] = M;
        ps[blk * 40 + tid] = S;
    }
}

__global__ void ksm_combine(const float* __restrict__ pm, const float* __restrict__ ps,
                            float* __restrict__ rmax, float* __restrict__ rsin) {
    int i = blockIdx.x * 256 + threadIdx.x;
    if (i >= 2560) return;
    int bh = i / 40, ch = i % 40;
    float M = -1e30f;
    for (int s = 0; s < 8; ++s) M = fmaxf(M, pm[(bh * 8 + s) * 40 + ch]);
    float S = 0.f;
    for (int s = 0; s < 8; ++s) S += ps[(bh * 8 + s) * 40 + ch] * __expf(pm[(bh * 8 + s) * 40 + ch] - M);
    rmax[i] = M;
    rsin[i] = 1.f / S;
}

// ---------------- kv = sum_n ksm[n,ch] * v[n,cv], split over N ----------------
// grid 512 ((b*8+h)*8+s), block 256. Writes partials (no atomics).
__global__ __launch_bounds__(256) void kv_kernel(const float* __restrict__ qkv,
                          const float* __restrict__ rmax, const float* __restrict__ rsin,
                          float* __restrict__ kvp) {
    int blk = blockIdx.x;
    int s = blk & 7;
    int bh = blk >> 3;
    int h = bh & 7, b = bh >> 3;
    int tid = threadIdx.x;
    __shared__ float ke[64][40];
    __shared__ float vv[64][40];
    float acc[7] = {};
    const float* kbase = qkv + (size_t)b * Nn * 960 + 320 + h * 40;
    const float* vbase = qkv + (size_t)b * Nn * 960 + 640 + h * 40;
    const float* rm = rmax + bh * 40;
    const float* rs = rsin + bh * 40;
    for (int c0 = 0; c0 < 512; c0 += 64) {
        int nb = s * 512 + c0;
        for (int e = tid; e < 2560; e += 256) {
            int nl = e / 40, ch = e % 40;
            size_t off = (size_t)(nb + nl) * 960 + ch;
            ke[nl][ch] = __expf(kbase[off] - rm[ch]) * rs[ch];
            vv[nl][ch] = vbase[off];
        }
        __syncthreads();
        #pragma unroll
        for (int j = 0; j < 7; ++j) {
            int p = tid + 256 * j;
            if (p < 1600) {
                int ch = p / 40, cv = p % 40;
                float a = acc[j];
                for (int nl = 0; nl < 64; ++nl)
                    a += ke[nl][ch] * vv[nl][cv];
                acc[j] = a;
            }
        }
        __syncthreads();
    }
    #pragma unroll
    for (int j = 0; j < 7; ++j) {
        int p = tid + 256 * j;
        if (p < 1600) kvp[(size_t)blk * 1600 + p] = acc[j];
    }
}

__global__ void kv_combine(const float* __restrict__ kvp, float* __restrict__ kv) {
    int i = blockIdx.x * 256 + threadIdx.x;  // < 102400
    int bh = i / 1600, p = i % 1600;
    float s = 0.f;
    for (int t = 0; t < 8; ++t) s += kvp[(size_t)(bh * 8 + t) * 1600 + p];
    kv[i] = s;
}

// ---------------- domain gate: MLP(one-hot) -> softmax over heads ----------------
// grid B, block 320
__global__ void dgate_kernel(const float* __restrict__ lbl, const float* __restrict__ w1,
                             const float* __restrict__ b1, const float* __restrict__ w2,
                             const float* __restrict__ b2, float* __restrict__ dg) {
    int b = blockIdx.x;
    int tid = threadIdx.x;
    __shared__ float hid[160];
    __shared__ float dd[320];
    if (tid < 160) {
        float a = b1[tid];
        for (int d = 0; d < 4; ++d) a += w1[tid * 4 + d] * lbl[b * 4 + d];
        hid[tid] = fmaxf(a, 0.f);
    }
    __syncthreads();
    float a = b2[tid];
    for (int j = 0; j < 160; ++j) a += w2[tid * 160 + j] * hid[j];
    dd[tid] = a;
    __syncthreads();
    if (tid < 40) {
        float M = -1e30f;
        for (int h2 = 0; h2 < 8; ++h2) M = fmaxf(M, dd[h2 * 40 + tid]);
        float S = 0.f;
        float e[8];
        for (int h2 = 0; h2 < 8; ++h2) { e[h2] = __expf(dd[h2 * 40 + tid] - M); S += e[h2]; }
        float inv = 1.f / S;
        for (int h2 = 0; h2 < 8; ++h2) dg[b * 320 + h2 * 40 + tid] = e[h2] * inv;
    }
}

// ---------------- att = dgate * (scale * q@kv + q * dwconv(v)) ----------------
// grid (B*N), block 320
__global__ void att_kernel(const float* __restrict__ qkv, const float* __restrict__ kvmat,
                           const float* __restrict__ dg,
                           const float* __restrict__ w3, const float* __restrict__ b3,
                           const float* __restrict__ w5, const float* __restrict__ b5,
                           const float* __restrict__ w7, const float* __restrict__ b7,
                           float* __restrict__ att) {
    int bn = blockIdx.x;
    int c  = threadIdx.x;
    int b  = bn >> 12, n = bn & 4095;
    int y  = n >> 6, xx = n & 63;
    int h  = c / 40, cv = c % 40;

    const float* vb = qkv + (size_t)b * Nn * 960 + 640 + c;
    int ksz;
    const float* wp;
    float conv;
    if (c < 80)       { ksz = 3; wp = w3 + c * 9;          conv = b3[c]; }
    else if (c < 200) { ksz = 5; wp = w5 + (c - 80) * 25;  conv = b5[c - 80]; }
    else              { ksz = 7; wp = w7 + (c - 200) * 49; conv = b7[c - 200]; }
    int p = ksz >> 1;
    for (int dy = -p; dy <= p; ++dy) {
        int yy = y + dy;
        if ((unsigned)yy >= 64u) continue;
        for (int dx = -p; dx <= p; ++dx) {
            int x2 = xx + dx;
            if ((unsigned)x2 >= 64u) continue;
            conv += vb[(size_t)((yy << 6) + x2) * 960] * wp[(dy + p) * ksz + (dx + p)];
        }
    }

    const float* qrow = qkv + (size_t)bn * 960 + h * 40;
    const float* kvc  = kvmat + (size_t)(b * 8 + h) * 1600 + cv;
    float fa = 0.f;
    #pragma unroll
    for (int ch = 0; ch < 40; ++ch) fa += qrow[ch] * kvc[ch * 40];
    float qv = qrow[cv];
    att[(size_t)bn * Cc + c] = dg[b * 320 + c] * (ATT_SCALE * fa + qv * conv);
}

extern "C" void kernel_launch(void* const* d_in, const int* in_sizes, int n_in,
                              void* d_out, int out_size, void* d_ws, size_t ws_size,
                              hipStream_t stream) {
    const float* x     = (const float*)d_in[0];
    const float* lbl   = (const float*)d_in[1];
    const float* cpe_w = (const float*)d_in[2];
    const float* cpe_b = (const float*)d_in[3];
    const float* ln1g  = (const float*)d_in[4];
    const float* ln1b  = (const float*)d_in[5];
    const float* qkv_w = (const float*)d_in[6];
    const float* qkv_b = (const float*)d_in[7];
    const float* w3    = (const float*)d_in[8];
    const float* b3    = (const float*)d_in[9];
    const float* w5    = (const float*)d_in[10];
    const float* b5    = (const float*)d_in[11];
    const float* w7    = (const float*)d_in[12];
    const float* b7    = (const float*)d_in[13];
    const float* dw1   = (const float*)d_in[14];
    const float* db1   = (const float*)d_in[15];
    const float* dw2   = (const float*)d_in[16];
    const float* db2   = (const float*)d_in[17];
    const float* pw    = (const float*)d_in[18];
    const float* pb    = (const float*)d_in[19];
    const float* ln2g  = (const float*)d_in[20];
    const float* ln2b  = (const float*)d_in[21];
    const float* m1w   = (const float*)d_in[22];
    const float* m1b   = (const float*)d_in[23];
    const float* m2w   = (const float*)d_in[24];
    const float* m2b   = (const float*)d_in[25];
    float* out = (float*)d_out;

    float* ws   = (float*)d_ws;
    float* x1   = ws; ws += 10485760;              // (B,N,C)
    float* cur  = ws; ws += 10485760;              // LN1 out -> att -> LN2 out
    float* big  = ws; ws += 41943040;              // qkv (31.4M) then mlp hidden (41.9M)
    float* pm   = ws; ws += 20480;
    float* ps   = ws; ws += 20480;
    float* rmax = ws; ws += 2560;
    float* rsin = ws; ws += 2560;
    float* kvp  = ws; ws += 819200;
    float* kv   = ws; ws += 102400;
    float* dg   = ws; ws += 2560;
    float* qkv  = big;
    float* mlph = big;

    // 1. CPE + residual
    cpe_kernel<<<B_ * Nn, 320, 0, stream>>>(x, cpe_w, cpe_b, x1);
    // 2. LN1
    ln_kernel<<<B_ * Nn, 64, 0, stream>>>(x1, ln1g, ln1b, cur);
    // 3. QKV GEMM  (32768 x 320) @ (960 x 320)^T
    {
        dim3 g(512, 15);
        gemm_kernel<0><<<g, 256, 0, stream>>>(cur, qkv_w, qkv_b, nullptr, qkv, 32768, 320, 960);
    }
    // 4. K column softmax stats
    ksm_partial<<<512, 320, 0, stream>>>(qkv, pm, ps);
    ksm_combine<<<10, 256, 0, stream>>>(pm, ps, rmax, rsin);
    // 5. kv = ksm^T v
    kv_kernel<<<512, 256, 0, stream>>>(qkv, rmax, rsin, kvp);
    kv_combine<<<400, 256, 0, stream>>>(kvp, kv);
    // 6. domain gate
    dgate_kernel<<<B_, 320, 0, stream>>>(lbl, dw1, db1, dw2, db2, dg);
    // 7. crpe conv + factor-att + gate -> att (into cur, qkv GEMM already consumed it)
    att_kernel<<<B_ * Nn, 320, 0, stream>>>(qkv, kv, dg, w3, b3, w5, b5, w7, b7, cur);
    // 8. proj GEMM + residual(x1) -> d_out (= x2)
    {
        dim3 g(512, 5);
        gemm_kernel<0><<<g, 256, 0, stream>>>(cur, pw, pb, x1, out, 32768, 320, 320);
    }
    // 9. LN2
    ln_kernel<<<B_ * Nn, 64, 0, stream>>>(out, ln2g, ln2b, cur);
    // 10. MLP1 + GELU
    {
        dim3 g(512, 20);
        gemm_kernel<1><<<g, 256, 0, stream>>>(cur, m1w, m1b, nullptr, mlph, 32768, 320, 1280);
    }
    // 11. MLP2 + residual(d_out) -> d_out
    {
        dim3 g(512, 5);
        gemm_kernel<0><<<g, 256, 0, stream>>>(mlph, m2w, m2b, out, out, 32768, 1280, 320);
    }
}

// Round 3
// 443.516 us; speedup vs baseline: 5.6483x; 5.6483x over previous
//
#include <hip/hip_runtime.h>
#include <hip/hip_bf16.h>
#include <math.h>
#include <type_traits>

#define B_    8
#define Nn    4096
#define Cc    320
#define ATT_SCALE 0.15811388300841897f

typedef __attribute__((ext_vector_type(8))) short s8v;
typedef __attribute__((ext_vector_type(4))) float f4v;

__device__ __forceinline__ float bf2f(short u) {
    return __uint_as_float(((unsigned int)(unsigned short)u) << 16);
}

// ---------------- fp32 -> bf16 convert ----------------
__global__ void cvt_bf16(const float* __restrict__ s, __hip_bfloat16* __restrict__ d, int n) {
    int i = blockIdx.x * 256 + threadIdx.x;
    if (i < n) d[i] = __float2bfloat16(s[i]);
}

// ---------------- LayerNorm over C=320, one wave per token, bf16 out ----------------
__global__ void ln_kernel(const float* __restrict__ x, const float* __restrict__ g,
                          const float* __restrict__ bt, __hip_bfloat16* __restrict__ out) {
    int bn = blockIdx.x;
    int lane = threadIdx.x;
    const float* row = x + (size_t)bn * Cc;
    float v[5];
    float s = 0.f, s2 = 0.f;
    #pragma unroll
    for (int i = 0; i < 5; ++i) {
        v[i] = row[lane + 64 * i];
        s += v[i];
        s2 += v[i] * v[i];
    }
    #pragma unroll
    for (int off = 32; off > 0; off >>= 1) {
        s  += __shfl_down(s, off);
        s2 += __shfl_down(s2, off);
    }
    s  = __shfl(s, 0);
    s2 = __shfl(s2, 0);
    float mean = s * (1.f / 320.f);
    float var  = s2 * (1.f / 320.f) - mean * mean;
    float rstd = rsqrtf(var + 1e-6f);
    __hip_bfloat16* orow = out + (size_t)bn * Cc;
    #pragma unroll
    for (int i = 0; i < 5; ++i) {
        int c = lane + 64 * i;
        orow[c] = __float2bfloat16((v[i] - mean) * rstd * g[c] + bt[c]);
    }
}

// ---------------- bf16 MFMA GEMM: out = A(MxK) @ W(NxK)^T + bias (+res)(+gelu) ----------------
// 128x64 tile, BK=32, 256 threads (4 waves 2x2), mfma_f32_16x16x32_bf16.
template<int ACT, int RES, int WF32, int WBF16>
__global__ __launch_bounds__(256) void gemm_bf16(
        const __hip_bfloat16* __restrict__ A, const __hip_bfloat16* __restrict__ W,
        const float* __restrict__ bias, const float* __restrict__ res,
        float* __restrict__ outf, __hip_bfloat16* __restrict__ outb,
        int M, int K, int N) {
    __shared__ short As[128][40];   // +8 pad: 2-way bank aliasing only (free)
    __shared__ short Bs[64][40];
    int tid = threadIdx.x;
    int m0 = blockIdx.x << 7;
    int n0 = blockIdx.y << 6;
    int w = tid >> 6, lane = tid & 63;
    int wr = w >> 1, wc = w & 1;
    int lrow = lane & 15, lk = lane >> 4;
    f4v acc[4][2];
    #pragma unroll
    for (int i = 0; i < 4; ++i)
        #pragma unroll
        for (int j = 0; j < 2; ++j) acc[i][j] = (f4v){0.f, 0.f, 0.f, 0.f};
    int arow = tid >> 1, akf = (tid & 1) << 4;
    int brow = tid >> 2, bkf = (tid & 3) << 3;
    for (int k0 = 0; k0 < K; k0 += 32) {
        __syncthreads();
        {
            const s8v* pa = reinterpret_cast<const s8v*>(&A[(size_t)(m0 + arow) * K + k0 + akf]);
            s8v a0 = pa[0];
            s8v a1 = pa[1];
            s8v b0 = *reinterpret_cast<const s8v*>(&W[(size_t)(n0 + brow) * K + k0 + bkf]);
            *reinterpret_cast<s8v*>(&As[arow][akf])     = a0;
            *reinterpret_cast<s8v*>(&As[arow][akf + 8]) = a1;
            *reinterpret_cast<s8v*>(&Bs[brow][bkf])     = b0;
        }
        __syncthreads();
        s8v af[4], bf[2];
        #pragma unroll
        for (int mi = 0; mi < 4; ++mi)
            af[mi] = *reinterpret_cast<const s8v*>(&As[wr * 64 + mi * 16 + lrow][lk * 8]);
        #pragma unroll
        for (int ni = 0; ni < 2; ++ni)
            bf[ni] = *reinterpret_cast<const s8v*>(&Bs[wc * 32 + ni * 16 + lrow][lk * 8]);
        #pragma unroll
        for (int mi = 0; mi < 4; ++mi)
            #pragma unroll
            for (int ni = 0; ni < 2; ++ni)
                acc[mi][ni] = __builtin_amdgcn_mfma_f32_16x16x32_bf16(af[mi], bf[ni], acc[mi][ni], 0, 0, 0);
    }
    #pragma unroll
    for (int mi = 0; mi < 4; ++mi) {
        #pragma unroll
        for (int ni = 0; ni < 2; ++ni) {
            #pragma unroll
            for (int r = 0; r < 4; ++r) {
                int m = m0 + wr * 64 + mi * 16 + lk * 4 + r;
                int n = n0 + wc * 32 + ni * 16 + lrow;
                float v = acc[mi][ni][r] + bias[n];
                if (RES) v += res[(size_t)m * N + n];
                if (ACT == 1) v = 0.5f * v * (1.f + erff(v * 0.70710678118654752f));
                if (WF32) outf[(size_t)m * N + n] = v;
                if (WBF16) outb[(size_t)m * N + n] = __float2bfloat16(v);
            }
        }
    }
}

// ---------------- tiled depthwise conv, block = (b, 8ch-group, 16x16 tile) ----------------
// EPI 0: cpe (out = conv + residual, fp32). EPI 1: att (out_bf16 = dg*(scale*fa + q*conv)).
// ST = src dtype (float for CPE on x, __hip_bfloat16 for crpe on qkv's v).
template<int KSZ, int EPI, typename ST>
__global__ __launch_bounds__(256) void dwconv_tile(
        const ST* __restrict__ src, int sstride, int scoff,
        const float* __restrict__ wts, const float* __restrict__ bias, int cbase, int ngrp,
        const float* __restrict__ aux0,   // EPI0: residual x ; EPI1: fa
        const float* __restrict__ aux1,   // EPI1: dg
        float* __restrict__ outf, __hip_bfloat16* __restrict__ outb) {
    constexpr int P = KSZ / 2;
    constexpr int S = 16 + 2 * P;
    __shared__ float vt[S * S * 8];
    __shared__ float ws_[8 * KSZ * KSZ];
    int blk = blockIdx.x;
    int tile = blk & 15;
    int g  = (blk >> 4) % ngrp;
    int b  = (blk >> 4) / ngrp;
    int ty0 = (tile >> 2) << 4;
    int tx0 = (tile & 3) << 4;
    int c0 = cbase + g * 8;
    int tid = threadIdx.x;
    for (int e = tid; e < 8 * KSZ * KSZ; e += 256)
        ws_[e] = wts[g * 8 * KSZ * KSZ + e];
    const ST* sb = src + (size_t)b * Nn * sstride + scoff + c0;
    for (int e = tid; e < S * S; e += 256) {
        int hy = e / S, hx = e % S;
        int gy = ty0 - P + hy, gx = tx0 - P + hx;
        float px8[8];
        #pragma unroll
        for (int j = 0; j < 8; ++j) px8[j] = 0.f;
        if ((unsigned)gy < 64u && (unsigned)gx < 64u) {
            const ST* p = &sb[(size_t)((gy << 6) + gx) * sstride];
            if constexpr (std::is_same<ST, float>::value) {
                float4 lo = reinterpret_cast<const float4*>(p)[0];
                float4 hi = reinterpret_cast<const float4*>(p)[1];
                px8[0] = lo.x; px8[1] = lo.y; px8[2] = lo.z; px8[3] = lo.w;
                px8[4] = hi.x; px8[5] = hi.y; px8[6] = hi.z; px8[7] = hi.w;
            } else {
                s8v v8 = *reinterpret_cast<const s8v*>(p);
                #pragma unroll
                for (int j = 0; j < 8; ++j) px8[j] = bf2f(v8[j]);
            }
        }
        #pragma unroll
        for (int j = 0; j < 8; ++j) vt[e * 8 + j] = px8[j];
    }
    __syncthreads();
    int cl  = tid & 7;
    int px  = (tid >> 3) & 15;
    int pyh = tid >> 7;
    int c = c0 + cl;
    float acc[8];
    float bval = bias[g * 8 + cl];
    #pragma unroll
    for (int j = 0; j < 8; ++j) acc[j] = bval;
    #pragma unroll
    for (int dx = 0; dx < KSZ; ++dx) {
        float col[8 + KSZ - 1];
        #pragma unroll
        for (int i = 0; i < 8 + KSZ - 1; ++i)
            col[i] = vt[((pyh * 8 + i) * S + (px + dx)) * 8 + cl];
        #pragma unroll
        for (int j = 0; j < 8; ++j)
            #pragma unroll
            for (int dy = 0; dy < KSZ; ++dy)
                acc[j] += col[j + dy] * ws_[cl * KSZ * KSZ + dy * KSZ + dx];
    }
    #pragma unroll
    for (int j = 0; j < 8; ++j) {
        int n = ((ty0 + pyh * 8 + j) << 6) + tx0 + px;
        size_t bn = (size_t)b * Nn + n;
        if (EPI == 0) {
            outf[bn * Cc + c] = acc[j] + aux0[bn * Cc + c];
        } else {
            float qv  = bf2f(((const short*)src)[bn * (size_t)sstride + c]);
            float fav = aux0[bn * Cc + c];
            float r = aux1[(size_t)b * Cc + c] * (ATT_SCALE * fav + qv * acc[j]);
            outb[bn * Cc + c] = __float2bfloat16(r);
        }
    }
}

// ---------------- K softmax over tokens: partial online (max,sum) ----------------
__global__ void ksm_partial(const __hip_bfloat16* __restrict__ qkv, float* __restrict__ pm,
                            float* __restrict__ ps) {
    int blk = blockIdx.x;
    int s = blk & 7;
    int bh = blk >> 3;
    int h = bh & 7, b = bh >> 3;
    int tid = threadIdx.x;
    int ch = tid % 40, seg = tid / 40;
    const short* base = (const short*)qkv + (size_t)b * Nn * 960 + 320 + h * 40 + ch;
    float m = -1e30f, sum = 0.f;
    int n0 = s * 512;
    for (int i = 0; i < 64; ++i) {
        int n = n0 + seg + i * 8;
        float kx = bf2f(base[(size_t)n * 960]);
        float mn = fmaxf(m, kx);
        sum = sum * __expf(m - mn) + __expf(kx - mn);
        m = mn;
    }
    __shared__ float sm[8][40], ss[8][40];
    sm[seg][ch] = m;
    ss[seg][ch] = sum;
    __syncthreads();
    if (tid < 40) {
        float M = -1e30f;
        for (int g2 = 0; g2 < 8; ++g2) M = fmaxf(M, sm[g2][tid]);
        float S = 0.f;
        for (int g2 = 0; g2 < 8; ++g2) S += ss[g2][tid] * __expf(sm[g2][tid] - M);
        pm[blk * 40 + tid] = M;
        ps[blk * 40 + tid] = S;
    }
}

__global__ void ksm_combine(const float* __restrict__ pm, const float* __restrict__ ps,
                            float* __restrict__ rmax, float* __restrict__ rsin) {
    int i = blockIdx.x * 256 + threadIdx.x;
    if (i >= 2560) return;
    float M = -1e30f;
    for (int s = 0; s < 8; ++s) M = fmaxf(M, pm[((i / 40) * 8 + s) * 40 + i % 40]);
    float S = 0.f;
    for (int s = 0; s < 8; ++s) S += ps[((i / 40) * 8 + s) * 40 + i % 40] * __expf(pm[((i / 40) * 8 + s) * 40 + i % 40] - M);
    rmax[i] = M;
    rsin[i] = 1.f / S;
}

// ---------------- kv = sum_n ksm[n,ch] * v[n,cv], split over N ----------------
__global__ __launch_bounds__(256) void kv_kernel(const __hip_bfloat16* __restrict__ qkv,
                          const float* __restrict__ rmax, const float* __restrict__ rsin,
                          float* __restrict__ kvp) {
    int blk = blockIdx.x;
    int s = blk & 7;
    int bh = blk >> 3;
    int h = bh & 7, b = bh >> 3;
    int tid = threadIdx.x;
    __shared__ float ke[64][40];
    __shared__ float vv[64][40];
    float acc[7] = {};
    const short* kbase = (const short*)qkv + (size_t)b * Nn * 960 + 320 + h * 40;
    const short* vbase = (const short*)qkv + (size_t)b * Nn * 960 + 640 + h * 40;
    const float* rm = rmax + bh * 40;
    const float* rs = rsin + bh * 40;
    for (int c0 = 0; c0 < 512; c0 += 64) {
        int nb = s * 512 + c0;
        for (int e = tid; e < 2560; e += 256) {
            int nl = e / 40, ch = e % 40;
            size_t off = (size_t)(nb + nl) * 960 + ch;
            ke[nl][ch] = __expf(bf2f(kbase[off]) - rm[ch]) * rs[ch];
            vv[nl][ch] = bf2f(vbase[off]);
        }
        __syncthreads();
        #pragma unroll
        for (int j = 0; j < 7; ++j) {
            int p = tid + 256 * j;
            if (p < 1600) {
                int ch = p / 40, cv = p % 40;
                float a = acc[j];
                for (int nl = 0; nl < 64; ++nl)
                    a += ke[nl][ch] * vv[nl][cv];
                acc[j] = a;
            }
        }
        __syncthreads();
    }
    #pragma unroll
    for (int j = 0; j < 7; ++j) {
        int p = tid + 256 * j;
        if (p < 1600) kvp[(size_t)blk * 1600 + p] = acc[j];
    }
}

__global__ void kv_combine(const float* __restrict__ kvp, float* __restrict__ kv) {
    int i = blockIdx.x * 256 + threadIdx.x;
    int bh = i / 1600, p = i % 1600;
    float s = 0.f;
    for (int t = 0; t < 8; ++t) s += kvp[(size_t)(bh * 8 + t) * 1600 + p];
    kv[i] = s;
}

// ---------------- domain gate ----------------
__global__ void dgate_kernel(const float* __restrict__ lbl, const float* __restrict__ w1,
                             const float* __restrict__ b1, const float* __restrict__ w2,
                             const float* __restrict__ b2, float* __restrict__ dg) {
    int b = blockIdx.x;
    int tid = threadIdx.x;
    __shared__ float hid[160];
    __shared__ float dd[320];
    if (tid < 160) {
        float a = b1[tid];
        for (int d = 0; d < 4; ++d) a += w1[tid * 4 + d] * lbl[b * 4 + d];
        hid[tid] = fmaxf(a, 0.f);
    }
    __syncthreads();
    float a = b2[tid];
    for (int j = 0; j < 160; ++j) a += w2[tid * 160 + j] * hid[j];
    dd[tid] = a;
    __syncthreads();
    if (tid < 40) {
        float M = -1e30f;
        for (int h2 = 0; h2 < 8; ++h2) M = fmaxf(M, dd[h2 * 40 + tid]);
        float S = 0.f;
        float e[8];
        for (int h2 = 0; h2 < 8; ++h2) { e[h2] = __expf(dd[h2 * 40 + tid] - M); S += e[h2]; }
        float inv = 1.f / S;
        for (int h2 = 0; h2 < 8; ++h2) dg[b * 320 + h2 * 40 + tid] = e[h2] * inv;
    }
}

// ---------------- fa = q @ kv, one token per thread ----------------
__global__ __launch_bounds__(256) void fa_kernel(const __hip_bfloat16* __restrict__ qkv,
        const float* __restrict__ kvmat, float* __restrict__ fa) {
    __shared__ float kvs[1600];
    int blk = blockIdx.x;
    int chunk = blk & 15;
    int bh = blk >> 4;
    int h = bh & 7, b = bh >> 3;
    int tid = threadIdx.x;
    for (int e = tid; e < 1600; e += 256) kvs[e] = kvmat[(size_t)bh * 1600 + e];
    __syncthreads();
    int n = chunk * 256 + tid;
    const short* qr = (const short*)qkv + (size_t)(b * Nn + n) * 960 + h * 40;
    float q[40];
    #pragma unroll
    for (int i = 0; i < 5; ++i) {
        s8v v8 = reinterpret_cast<const s8v*>(qr)[i];
        #pragma unroll
        for (int j = 0; j < 8; ++j) q[i * 8 + j] = bf2f(v8[j]);
    }
    float o[40];
    #pragma unroll
    for (int cv = 0; cv < 40; ++cv) o[cv] = 0.f;
    #pragma unroll
    for (int ch = 0; ch < 40; ++ch) {
        float qv = q[ch];
        #pragma unroll
        for (int cv = 0; cv < 40; ++cv)
            o[cv] += qv * kvs[ch * 40 + cv];
    }
    float* fr = fa + (size_t)(b * Nn + n) * 320 + h * 40;
    #pragma unroll
    for (int i = 0; i < 10; ++i)
        reinterpret_cast<float4*>(fr)[i] = make_float4(o[i * 4], o[i * 4 + 1], o[i * 4 + 2], o[i * 4 + 3]);
}

extern "C" void kernel_launch(void* const* d_in, const int* in_sizes, int n_in,
                              void* d_out, int out_size, void* d_ws, size_t ws_size,
                              hipStream_t stream) {
    const float* x     = (const float*)d_in[0];
    const float* lbl   = (const float*)d_in[1];
    const float* cpe_w = (const float*)d_in[2];
    const float* cpe_b = (const float*)d_in[3];
    const float* ln1g  = (const float*)d_in[4];
    const float* ln1b  = (const float*)d_in[5];
    const float* qkv_w = (const float*)d_in[6];
    const float* qkv_b = (const float*)d_in[7];
    const float* w3    = (const float*)d_in[8];
    const float* b3    = (const float*)d_in[9];
    const float* w5    = (const float*)d_in[10];
    const float* b5    = (const float*)d_in[11];
    const float* w7    = (const float*)d_in[12];
    const float* b7    = (const float*)d_in[13];
    const float* dw1   = (const float*)d_in[14];
    const float* db1   = (const float*)d_in[15];
    const float* dw2   = (const float*)d_in[16];
    const float* db2   = (const float*)d_in[17];
    const float* pw    = (const float*)d_in[18];
    const float* pb    = (const float*)d_in[19];
    const float* ln2g  = (const float*)d_in[20];
    const float* ln2b  = (const float*)d_in[21];
    const float* m1w   = (const float*)d_in[22];
    const float* m1b   = (const float*)d_in[23];
    const float* m2w   = (const float*)d_in[24];
    const float* m2b   = (const float*)d_in[25];
    float* out = (float*)d_out;

    // ws budget (floats): total 54,013,440 = 206 MB (R1's working 255 MB was OK)
    float* ws = (float*)d_ws;
    float* x1   = ws; ws += 10485760;                           // (B,N,C) fp32
    __hip_bfloat16* qkvb = (__hip_bfloat16*)ws; ws += 15728640; // (B,N,960) bf16
    float* fa   = ws; ws += 20971520;                           // fa fp32 (10.49M fl) / gelu bf16 (41.94M) union
    __hip_bfloat16* gelub = (__hip_bfloat16*)fa;
    __hip_bfloat16* bb1   = (__hip_bfloat16*)ws; ws += 5242880; // (B,N,C) bf16 (ln1/att/ln2 outs)
    __hip_bfloat16* wb    = (__hip_bfloat16*)ws; ws += 614400;  // 1,228,800 bf16 weights
    float* pm   = ws; ws += 20480;
    float* ps   = ws; ws += 20480;
    float* rmax = ws; ws += 2560;
    float* rsin = ws; ws += 2560;
    float* kvp  = ws; ws += 819200;
    float* kv   = ws; ws += 102400;
    float* dg   = ws; ws += 2560;
    __hip_bfloat16* wbq  = wb;
    __hip_bfloat16* wbp  = wb + 307200;
    __hip_bfloat16* wbm1 = wb + 409600;
    __hip_bfloat16* wbm2 = wb + 819200;

    // 0. weights -> bf16
    cvt_bf16<<<1200, 256, 0, stream>>>(qkv_w, wbq, 307200);
    cvt_bf16<<<400,  256, 0, stream>>>(pw,    wbp, 102400);
    cvt_bf16<<<1600, 256, 0, stream>>>(m1w,   wbm1, 409600);
    cvt_bf16<<<1600, 256, 0, stream>>>(m2w,   wbm2, 409600);
    // 1. CPE conv + residual -> x1 (fp32)
    dwconv_tile<3, 0, float><<<B_ * 40 * 16, 256, 0, stream>>>(
        x, 320, 0, cpe_w, cpe_b, 0, 40, x, nullptr, x1, nullptr);
    // 2. LN1 -> bb1 (bf16)
    ln_kernel<<<B_ * Nn, 64, 0, stream>>>(x1, ln1g, ln1b, bb1);
    // 3. QKV GEMM -> qkvb (bf16)
    {
        dim3 g(256, 15);
        gemm_bf16<0, 0, 0, 1><<<g, 256, 0, stream>>>(bb1, wbq, qkv_b, nullptr, nullptr, qkvb,
                                                     32768, 320, 960);
    }
    // 4. K column softmax stats
    ksm_partial<<<512, 320, 0, stream>>>(qkvb, pm, ps);
    ksm_combine<<<10, 256, 0, stream>>>(pm, ps, rmax, rsin);
    // 5. kv
    kv_kernel<<<512, 256, 0, stream>>>(qkvb, rmax, rsin, kvp);
    kv_combine<<<400, 256, 0, stream>>>(kvp, kv);
    // 6. domain gate
    dgate_kernel<<<B_, 320, 0, stream>>>(lbl, dw1, db1, dw2, db2, dg);
    // 7. fa = q @ kv
    fa_kernel<<<B_ * 8 * 16, 256, 0, stream>>>(qkvb, kv, fa);
    // 8. crpe conv + combine -> bb1 (bf16 att)
    dwconv_tile<3, 1, __hip_bfloat16><<<B_ * 10 * 16, 256, 0, stream>>>(
        qkvb, 960, 640, w3, b3, 0, 10, fa, dg, nullptr, bb1);
    dwconv_tile<5, 1, __hip_bfloat16><<<B_ * 15 * 16, 256, 0, stream>>>(
        qkvb, 960, 640, w5, b5, 80, 15, fa, dg, nullptr, bb1);
    dwconv_tile<7, 1, __hip_bfloat16><<<B_ * 15 * 16, 256, 0, stream>>>(
        qkvb, 960, 640, w7, b7, 200, 15, fa, dg, nullptr, bb1);
    // 9. proj GEMM + residual(x1) -> d_out
    {
        dim3 g(256, 5);
        gemm_bf16<0, 1, 1, 0><<<g, 256, 0, stream>>>(bb1, wbp, pb, x1, out, nullptr,
                                                     32768, 320, 320);
    }
    // 10. LN2 -> bb1
    ln_kernel<<<B_ * Nn, 64, 0, stream>>>(out, ln2g, ln2b, bb1);
    // 11. MLP1 + GELU -> gelub (bf16)
    {
        dim3 g(256, 20);
        gemm_bf16<1, 0, 0, 1><<<g, 256, 0, stream>>>(bb1, wbm1, m1b, nullptr, nullptr, gelub,
                                                     32768, 320, 1280);
    }
    // 12. MLP2 + residual(d_out) -> d_out
    {
        dim3 g(256, 5);
        gemm_bf16<0, 1, 1, 0><<<g, 256, 0, stream>>>(gelub, wbm2, m2b, out, out, nullptr,
                                                     32768, 1280, 320);
    }
}

// Round 4
// 375.392 us; speedup vs baseline: 6.6733x; 1.1815x over previous
//
#include <hip/hip_runtime.h>
#include <hip/hip_bf16.h>
#include <math.h>
#include <type_traits>

#define B_    8
#define Nn    4096
#define Cc    320
#define ATT_SCALE 0.15811388300841897f

typedef __attribute__((ext_vector_type(8))) short s8v;
typedef __attribute__((ext_vector_type(4))) float f4v;

__device__ __forceinline__ float bf2f(short u) {
    return __uint_as_float(((unsigned int)(unsigned short)u) << 16);
}
__device__ __forceinline__ short f2bf(float f) {
    return (short)__bfloat16_as_ushort(__float2bfloat16(f));
}

// ---------------- fp32 -> bf16 convert ----------------
__global__ void cvt_bf16(const float* __restrict__ s, __hip_bfloat16* __restrict__ d, int n) {
    int i = blockIdx.x * 256 + threadIdx.x;
    if (i < n) d[i] = __float2bfloat16(s[i]);
}

// ---------------- LayerNorm over C=320, one wave per token, bf16 out ----------------
__global__ void ln_kernel(const float* __restrict__ x, const float* __restrict__ g,
                          const float* __restrict__ bt, __hip_bfloat16* __restrict__ out) {
    int bn = blockIdx.x;
    int lane = threadIdx.x;
    const float* row = x + (size_t)bn * Cc;
    float v[5];
    float s = 0.f, s2 = 0.f;
    #pragma unroll
    for (int i = 0; i < 5; ++i) {
        v[i] = row[lane + 64 * i];
        s += v[i];
        s2 += v[i] * v[i];
    }
    #pragma unroll
    for (int off = 32; off > 0; off >>= 1) {
        s  += __shfl_down(s, off);
        s2 += __shfl_down(s2, off);
    }
    s  = __shfl(s, 0);
    s2 = __shfl(s2, 0);
    float mean = s * (1.f / 320.f);
    float var  = s2 * (1.f / 320.f) - mean * mean;
    float rstd = rsqrtf(var + 1e-6f);
    __hip_bfloat16* orow = out + (size_t)bn * Cc;
    #pragma unroll
    for (int i = 0; i < 5; ++i) {
        int c = lane + 64 * i;
        orow[c] = __float2bfloat16((v[i] - mean) * rstd * g[c] + bt[c]);
    }
}

// ---------------- bf16 MFMA GEMM: out = A(MxK) @ W(NxK)^T + bias (+res)(+gelu) ----------------
// 128x64 tile, BK=32, 256 threads (4 waves 2x2), mfma_f32_16x16x32_bf16.
template<int ACT, int RES, int WF32, int WBF16>
__global__ __launch_bounds__(256) void gemm_bf16(
        const __hip_bfloat16* __restrict__ A, const __hip_bfloat16* __restrict__ W,
        const float* __restrict__ bias, const float* __restrict__ res,
        float* __restrict__ outf, __hip_bfloat16* __restrict__ outb,
        int M, int K, int N) {
    __shared__ short As[128][40];   // +8 pad: 2-way bank aliasing only (free)
    __shared__ short Bs[64][40];
    int tid = threadIdx.x;
    int m0 = blockIdx.x << 7;
    int n0 = blockIdx.y << 6;
    int w = tid >> 6, lane = tid & 63;
    int wr = w >> 1, wc = w & 1;
    int lrow = lane & 15, lk = lane >> 4;
    f4v acc[4][2];
    #pragma unroll
    for (int i = 0; i < 4; ++i)
        #pragma unroll
        for (int j = 0; j < 2; ++j) acc[i][j] = (f4v){0.f, 0.f, 0.f, 0.f};
    int arow = tid >> 1, akf = (tid & 1) << 4;
    int brow = tid >> 2, bkf = (tid & 3) << 3;
    for (int k0 = 0; k0 < K; k0 += 32) {
        __syncthreads();
        {
            const s8v* pa = reinterpret_cast<const s8v*>(&A[(size_t)(m0 + arow) * K + k0 + akf]);
            s8v a0 = pa[0];
            s8v a1 = pa[1];
            s8v b0 = *reinterpret_cast<const s8v*>(&W[(size_t)(n0 + brow) * K + k0 + bkf]);
            *reinterpret_cast<s8v*>(&As[arow][akf])     = a0;
            *reinterpret_cast<s8v*>(&As[arow][akf + 8]) = a1;
            *reinterpret_cast<s8v*>(&Bs[brow][bkf])     = b0;
        }
        __syncthreads();
        s8v af[4], bf[2];
        #pragma unroll
        for (int mi = 0; mi < 4; ++mi)
            af[mi] = *reinterpret_cast<const s8v*>(&As[wr * 64 + mi * 16 + lrow][lk * 8]);
        #pragma unroll
        for (int ni = 0; ni < 2; ++ni)
            bf[ni] = *reinterpret_cast<const s8v*>(&Bs[wc * 32 + ni * 16 + lrow][lk * 8]);
        #pragma unroll
        for (int mi = 0; mi < 4; ++mi)
            #pragma unroll
            for (int ni = 0; ni < 2; ++ni)
                acc[mi][ni] = __builtin_amdgcn_mfma_f32_16x16x32_bf16(af[mi], bf[ni], acc[mi][ni], 0, 0, 0);
    }
    #pragma unroll
    for (int mi = 0; mi < 4; ++mi) {
        #pragma unroll
        for (int ni = 0; ni < 2; ++ni) {
            #pragma unroll
            for (int r = 0; r < 4; ++r) {
                int m = m0 + wr * 64 + mi * 16 + lk * 4 + r;
                int n = n0 + wc * 32 + ni * 16 + lrow;
                float v = acc[mi][ni][r] + bias[n];
                if (RES) v += res[(size_t)m * N + n];
                if (ACT == 1) v = 0.5f * v * (1.f + erff(v * 0.70710678118654752f));
                if (WF32) outf[(size_t)m * N + n] = v;
                if (WBF16) outb[(size_t)m * N + n] = __float2bfloat16(v);
            }
        }
    }
}

// ---------------- tiled depthwise conv, block = (b, 8ch-group, 16x16 tile) ----------------
// EPI 0: cpe (out = conv + residual, fp32). EPI 1: att (out_bf16 = dg*(scale*fa + q*conv)).
template<int KSZ, int EPI, typename ST>
__global__ __launch_bounds__(256) void dwconv_tile(
        const ST* __restrict__ src, int sstride, int scoff,
        const float* __restrict__ wts, const float* __restrict__ bias, int cbase, int ngrp,
        const float* __restrict__ aux0,   // EPI0: residual x ; EPI1: fa
        const float* __restrict__ aux1,   // EPI1: dg
        float* __restrict__ outf, __hip_bfloat16* __restrict__ outb) {
    constexpr int P = KSZ / 2;
    constexpr int S = 16 + 2 * P;
    __shared__ float vt[S * S * 8];
    __shared__ float ws_[8 * KSZ * KSZ];
    int blk = blockIdx.x;
    int tile = blk & 15;
    int g  = (blk >> 4) % ngrp;
    int b  = (blk >> 4) / ngrp;
    int ty0 = (tile >> 2) << 4;
    int tx0 = (tile & 3) << 4;
    int c0 = cbase + g * 8;
    int tid = threadIdx.x;
    for (int e = tid; e < 8 * KSZ * KSZ; e += 256)
        ws_[e] = wts[g * 8 * KSZ * KSZ + e];
    const ST* sb = src + (size_t)b * Nn * sstride + scoff + c0;
    for (int e = tid; e < S * S; e += 256) {
        int hy = e / S, hx = e % S;
        int gy = ty0 - P + hy, gx = tx0 - P + hx;
        float px8[8];
        #pragma unroll
        for (int j = 0; j < 8; ++j) px8[j] = 0.f;
        if ((unsigned)gy < 64u && (unsigned)gx < 64u) {
            const ST* p = &sb[(size_t)((gy << 6) + gx) * sstride];
            if constexpr (std::is_same<ST, float>::value) {
                float4 lo = reinterpret_cast<const float4*>(p)[0];
                float4 hi = reinterpret_cast<const float4*>(p)[1];
                px8[0] = lo.x; px8[1] = lo.y; px8[2] = lo.z; px8[3] = lo.w;
                px8[4] = hi.x; px8[5] = hi.y; px8[6] = hi.z; px8[7] = hi.w;
            } else {
                s8v v8 = *reinterpret_cast<const s8v*>(p);
                #pragma unroll
                for (int j = 0; j < 8; ++j) px8[j] = bf2f(v8[j]);
            }
        }
        #pragma unroll
        for (int j = 0; j < 8; ++j) vt[e * 8 + j] = px8[j];
    }
    __syncthreads();
    int cl  = tid & 7;
    int px  = (tid >> 3) & 15;
    int pyh = tid >> 7;
    int c = c0 + cl;
    float acc[8];
    float bval = bias[g * 8 + cl];
    #pragma unroll
    for (int j = 0; j < 8; ++j) acc[j] = bval;
    #pragma unroll
    for (int dx = 0; dx < KSZ; ++dx) {
        float col[8 + KSZ - 1];
        #pragma unroll
        for (int i = 0; i < 8 + KSZ - 1; ++i)
            col[i] = vt[((pyh * 8 + i) * S + (px + dx)) * 8 + cl];
        #pragma unroll
        for (int j = 0; j < 8; ++j)
            #pragma unroll
            for (int dy = 0; dy < KSZ; ++dy)
                acc[j] += col[j + dy] * ws_[cl * KSZ * KSZ + dy * KSZ + dx];
    }
    #pragma unroll
    for (int j = 0; j < 8; ++j) {
        int n = ((ty0 + pyh * 8 + j) << 6) + tx0 + px;
        size_t bn = (size_t)b * Nn + n;
        if (EPI == 0) {
            outf[bn * Cc + c] = acc[j] + aux0[bn * Cc + c];
        } else {
            float qv  = bf2f(((const short*)src)[bn * (size_t)sstride + c]);
            float fav = aux0[bn * Cc + c];
            float r = aux1[(size_t)b * Cc + c] * (ATT_SCALE * fav + qv * acc[j]);
            outb[bn * Cc + c] = __float2bfloat16(r);
        }
    }
}

// ---------------- kv + softmax-denominator via MFMA ----------------
// kv[ch][cv] = sum_n exp(k[n,ch]) * v[n,cv];  column 40 of B-tile = ones => D[ch][40] = S[ch].
// grid 512 = (bh, s in 0..7), block 256 (4 waves, each owns 2x 64-token tiles).
// Per wave: ke_t[48][66] / vv_t[48][66] bf16 transposed LDS tiles (pad 66: conflict-free),
// 18 mfma_f32_16x16x32_bf16 per tile (3x3 output tiles of 48x48, K=64).
__global__ __launch_bounds__(256) void kv_mfma(const __hip_bfloat16* __restrict__ qkv,
                                               float* __restrict__ kvp) {
    __shared__ short lds[4 * 2 * 48 * 66];   // 50688 B; reused as float red[4][1920] at the end
    int blk = blockIdx.x;
    int s = blk & 7;
    int bh = blk >> 3;
    int h = bh & 7, b = bh >> 3;
    int tid = threadIdx.x;
    int w = tid >> 6, lane = tid & 63;
    short* ke_t = lds + w * 2 * 48 * 66;
    short* vv_t = ke_t + 48 * 66;
    // zero pad rows 40..47, then vv_t row 40 = 1.0 (denominator column)
    for (int e = lane; e < 8 * 66; e += 64) {
        ke_t[40 * 66 + e] = 0;
        vv_t[40 * 66 + e] = 0;
    }
    for (int n = lane; n < 66; n += 64) vv_t[40 * 66 + n] = (short)0x3F80;

    const short* kb = (const short*)qkv + (size_t)b * Nn * 960 + 320 + h * 40;
    const short* vb = kb + 320;
    int col0 = lane & 15, kq = lane >> 4;
    f4v acc[3][3];
    #pragma unroll
    for (int i = 0; i < 3; ++i)
        #pragma unroll
        for (int j = 0; j < 3; ++j) acc[i][j] = (f4v){0.f, 0.f, 0.f, 0.f};

    for (int t = w; t < 8; t += 4) {
        int n0 = s * 512 + t * 64;
        for (int e = lane; e < 320; e += 64) {
            int nl = e / 5, oct = e % 5;
            size_t go = (size_t)(n0 + nl) * 960 + oct * 8;
            s8v k8 = *reinterpret_cast<const s8v*>(kb + go);
            s8v v8 = *reinterpret_cast<const s8v*>(vb + go);
            #pragma unroll
            for (int j = 0; j < 8; ++j) {
                ke_t[(oct * 8 + j) * 66 + nl] = f2bf(__expf(bf2f(k8[j])));
                vv_t[(oct * 8 + j) * 66 + nl] = v8[j];
            }
        }
        __syncthreads();   // all waves same trip count; also orders own-wave LDS writes->reads
        #pragma unroll
        for (int ks = 0; ks < 2; ++ks) {
            s8v af[3], bfr[3];
            #pragma unroll
            for (int mt = 0; mt < 3; ++mt)
                af[mt] = *reinterpret_cast<const s8v*>(ke_t + (mt * 16 + col0) * 66 + ks * 32 + kq * 8);
            #pragma unroll
            for (int nt = 0; nt < 3; ++nt)
                bfr[nt] = *reinterpret_cast<const s8v*>(vv_t + (nt * 16 + col0) * 66 + ks * 32 + kq * 8);
            #pragma unroll
            for (int mt = 0; mt < 3; ++mt)
                #pragma unroll
                for (int nt = 0; nt < 3; ++nt)
                    acc[mt][nt] = __builtin_amdgcn_mfma_f32_16x16x32_bf16(af[mt], bfr[nt], acc[mt][nt], 0, 0, 0);
        }
        __syncthreads();   // before restaging over the just-read tiles
    }
    // cross-wave reduce via LDS (overlays tile storage — all compute done)
    float* red = (float*)lds;   // 4 * 1920 floats = 30720 B
    #pragma unroll
    for (int mt = 0; mt < 3; ++mt) {
        #pragma unroll
        for (int nt = 0; nt < 3; ++nt) {
            #pragma unroll
            for (int r = 0; r < 4; ++r) {
                int ch = mt * 16 + kq * 4 + r;
                int cv = nt * 16 + col0;
                if (ch < 40) red[w * 1920 + ch * 48 + cv] = acc[mt][nt][r];
            }
        }
    }
    __syncthreads();
    for (int p = tid; p < 1920; p += 256) {
        float sv = red[p] + red[1920 + p] + red[2 * 1920 + p] + red[3 * 1920 + p];
        kvp[(size_t)blk * 1920 + p] = sv;
    }
}

// combine 8 N-split partials, normalize by S[ch] (column 40). grid 64 (bh), block 256.
__global__ void kv_combine2(const float* __restrict__ kvp, float* __restrict__ kv) {
    int bh = blockIdx.x;
    int tid = threadIdx.x;
    __shared__ float sinv[40];
    if (tid < 40) {
        float S = 0.f;
        for (int s2 = 0; s2 < 8; ++s2)
            S += kvp[(size_t)(bh * 8 + s2) * 1920 + tid * 48 + 40];
        sinv[tid] = 1.f / S;
    }
    __syncthreads();
    for (int p = tid; p < 1600; p += 256) {
        int ch = p / 40, cv = p % 40;
        float v = 0.f;
        for (int s2 = 0; s2 < 8; ++s2)
            v += kvp[(size_t)(bh * 8 + s2) * 1920 + ch * 48 + cv];
        kv[(size_t)bh * 1600 + p] = v * sinv[ch];
    }
}

// ---------------- domain gate ----------------
__global__ void dgate_kernel(const float* __restrict__ lbl, const float* __restrict__ w1,
                             const float* __restrict__ b1, const float* __restrict__ w2,
                             const float* __restrict__ b2, float* __restrict__ dg) {
    int b = blockIdx.x;
    int tid = threadIdx.x;
    __shared__ float hid[160];
    __shared__ float dd[320];
    if (tid < 160) {
        float a = b1[tid];
        for (int d = 0; d < 4; ++d) a += w1[tid * 4 + d] * lbl[b * 4 + d];
        hid[tid] = fmaxf(a, 0.f);
    }
    __syncthreads();
    float a = b2[tid];
    for (int j = 0; j < 160; ++j) a += w2[tid * 160 + j] * hid[j];
    dd[tid] = a;
    __syncthreads();
    if (tid < 40) {
        float M = -1e30f;
        for (int h2 = 0; h2 < 8; ++h2) M = fmaxf(M, dd[h2 * 40 + tid]);
        float S = 0.f;
        float e[8];
        for (int h2 = 0; h2 < 8; ++h2) { e[h2] = __expf(dd[h2 * 40 + tid] - M); S += e[h2]; }
        float inv = 1.f / S;
        for (int h2 = 0; h2 < 8; ++h2) dg[b * 320 + h2 * 40 + tid] = e[h2] * inv;
    }
}

// ---------------- fa = q @ kv, one token per thread ----------------
__global__ __launch_bounds__(256) void fa_kernel(const __hip_bfloat16* __restrict__ qkv,
        const float* __restrict__ kvmat, float* __restrict__ fa) {
    __shared__ float kvs[1600];
    int blk = blockIdx.x;
    int chunk = blk & 15;
    int bh = blk >> 4;
    int h = bh & 7, b = bh >> 3;
    int tid = threadIdx.x;
    for (int e = tid; e < 1600; e += 256) kvs[e] = kvmat[(size_t)bh * 1600 + e];
    __syncthreads();
    int n = chunk * 256 + tid;
    const short* qr = (const short*)qkv + (size_t)(b * Nn + n) * 960 + h * 40;
    float q[40];
    #pragma unroll
    for (int i = 0; i < 5; ++i) {
        s8v v8 = reinterpret_cast<const s8v*>(qr)[i];
        #pragma unroll
        for (int j = 0; j < 8; ++j) q[i * 8 + j] = bf2f(v8[j]);
    }
    float o[40];
    #pragma unroll
    for (int cv = 0; cv < 40; ++cv) o[cv] = 0.f;
    #pragma unroll
    for (int ch = 0; ch < 40; ++ch) {
        float qv = q[ch];
        #pragma unroll
        for (int cv = 0; cv < 40; ++cv)
            o[cv] += qv * kvs[ch * 40 + cv];
    }
    float* fr = fa + (size_t)(b * Nn + n) * 320 + h * 40;
    #pragma unroll
    for (int i = 0; i < 10; ++i)
        reinterpret_cast<float4*>(fr)[i] = make_float4(o[i * 4], o[i * 4 + 1], o[i * 4 + 2], o[i * 4 + 3]);
}

extern "C" void kernel_launch(void* const* d_in, const int* in_sizes, int n_in,
                              void* d_out, int out_size, void* d_ws, size_t ws_size,
                              hipStream_t stream) {
    const float* x     = (const float*)d_in[0];
    const float* lbl   = (const float*)d_in[1];
    const float* cpe_w = (const float*)d_in[2];
    const float* cpe_b = (const float*)d_in[3];
    const float* ln1g  = (const float*)d_in[4];
    const float* ln1b  = (const float*)d_in[5];
    const float* qkv_w = (const float*)d_in[6];
    const float* qkv_b = (const float*)d_in[7];
    const float* w3    = (const float*)d_in[8];
    const float* b3    = (const float*)d_in[9];
    const float* w5    = (const float*)d_in[10];
    const float* b5    = (const float*)d_in[11];
    const float* w7    = (const float*)d_in[12];
    const float* b7    = (const float*)d_in[13];
    const float* dw1   = (const float*)d_in[14];
    const float* db1   = (const float*)d_in[15];
    const float* dw2   = (const float*)d_in[16];
    const float* db2   = (const float*)d_in[17];
    const float* pw    = (const float*)d_in[18];
    const float* pb    = (const float*)d_in[19];
    const float* ln2g  = (const float*)d_in[20];
    const float* ln2b  = (const float*)d_in[21];
    const float* m1w   = (const float*)d_in[22];
    const float* m1b   = (const float*)d_in[23];
    const float* m2w   = (const float*)d_in[24];
    const float* m2b   = (const float*)d_in[25];
    float* out = (float*)d_out;

    // ws budget (floats): ~54.1M = 216 MB
    float* ws = (float*)d_ws;
    float* x1   = ws; ws += 10485760;                           // (B,N,C) fp32
    __hip_bfloat16* qkvb = (__hip_bfloat16*)ws; ws += 15728640; // (B,N,960) bf16
    float* fa   = ws; ws += 20971520;                           // fa fp32 / gelu bf16 union
    __hip_bfloat16* gelub = (__hip_bfloat16*)fa;
    __hip_bfloat16* bb1   = (__hip_bfloat16*)ws; ws += 5242880; // (B,N,C) bf16
    __hip_bfloat16* wb    = (__hip_bfloat16*)ws; ws += 614400;  // bf16 weights
    float* kvp  = ws; ws += 983040;                             // 512 x 1920
    float* kv   = ws; ws += 102400;
    float* dg   = ws; ws += 2560;
    __hip_bfloat16* wbq  = wb;
    __hip_bfloat16* wbp  = wb + 307200;
    __hip_bfloat16* wbm1 = wb + 409600;
    __hip_bfloat16* wbm2 = wb + 819200;

    // 0. weights -> bf16
    cvt_bf16<<<1200, 256, 0, stream>>>(qkv_w, wbq, 307200);
    cvt_bf16<<<400,  256, 0, stream>>>(pw,    wbp, 102400);
    cvt_bf16<<<1600, 256, 0, stream>>>(m1w,   wbm1, 409600);
    cvt_bf16<<<1600, 256, 0, stream>>>(m2w,   wbm2, 409600);
    // 1. CPE conv + residual -> x1 (fp32)
    dwconv_tile<3, 0, float><<<B_ * 40 * 16, 256, 0, stream>>>(
        x, 320, 0, cpe_w, cpe_b, 0, 40, x, nullptr, x1, nullptr);
    // 2. LN1 -> bb1 (bf16)
    ln_kernel<<<B_ * Nn, 64, 0, stream>>>(x1, ln1g, ln1b, bb1);
    // 3. QKV GEMM -> qkvb (bf16)
    {
        dim3 g(256, 15);
        gemm_bf16<0, 0, 0, 1><<<g, 256, 0, stream>>>(bb1, wbq, qkv_b, nullptr, nullptr, qkvb,
                                                     32768, 320, 960);
    }
    // 4. kv (+ softmax denominator) via MFMA
    kv_mfma<<<512, 256, 0, stream>>>(qkvb, kvp);
    kv_combine2<<<64, 256, 0, stream>>>(kvp, kv);
    // 5. domain gate
    dgate_kernel<<<B_, 320, 0, stream>>>(lbl, dw1, db1, dw2, db2, dg);
    // 6. fa = q @ kv
    fa_kernel<<<B_ * 8 * 16, 256, 0, stream>>>(qkvb, kv, fa);
    // 7. crpe conv + combine -> bb1 (bf16 att)
    dwconv_tile<3, 1, __hip_bfloat16><<<B_ * 10 * 16, 256, 0, stream>>>(
        qkvb, 960, 640, w3, b3, 0, 10, fa, dg, nullptr, bb1);
    dwconv_tile<5, 1, __hip_bfloat16><<<B_ * 15 * 16, 256, 0, stream>>>(
        qkvb, 960, 640, w5, b5, 80, 15, fa, dg, nullptr, bb1);
    dwconv_tile<7, 1, __hip_bfloat16><<<B_ * 15 * 16, 256, 0, stream>>>(
        qkvb, 960, 640, w7, b7, 200, 15, fa, dg, nullptr, bb1);
    // 8. proj GEMM + residual(x1) -> d_out
    {
        dim3 g(256, 5);
        gemm_bf16<0, 1, 1, 0><<<g, 256, 0, stream>>>(bb1, wbp, pb, x1, out, nullptr,
                                                     32768, 320, 320);
    }
    // 9. LN2 -> bb1
    ln_kernel<<<B_ * Nn, 64, 0, stream>>>(out, ln2g, ln2b, bb1);
    // 10. MLP1 + GELU -> gelub (bf16)
    {
        dim3 g(256, 20);
        gemm_bf16<1, 0, 0, 1><<<g, 256, 0, stream>>>(bb1, wbm1, m1b, nullptr, nullptr, gelub,
                                                     32768, 320, 1280);
    }
    // 11. MLP2 + residual(d_out) -> d_out
    {
        dim3 g(256, 5);
        gemm_bf16<0, 1, 1, 0><<<g, 256, 0, stream>>>(gelub, wbm2, m2b, out, out, nullptr,
                                                     32768, 1280, 320);
    }
}

// Round 5
// 360.262 us; speedup vs baseline: 6.9535x; 1.0420x over previous
//
#include <hip/hip_runtime.h>
#include <hip/hip_bf16.h>
#include <math.h>
#include <type_traits>

#define B_    8
#define Nn    4096
#define Cc    320
#define QS    1024          // qkv row stride (padded from 960)
#define ATT_SCALE 0.15811388300841897f

typedef __attribute__((ext_vector_type(8))) short s8v;
typedef __attribute__((ext_vector_type(4))) float f4v;

__device__ __forceinline__ float bf2f(short u) {
    return __uint_as_float(((unsigned int)(unsigned short)u) << 16);
}
__device__ __forceinline__ short f2bf(float f) {
    return (short)__bfloat16_as_ushort(__float2bfloat16(f));
}

typedef const __attribute__((address_space(1))) unsigned int* gp1_t;
typedef __attribute__((address_space(3))) unsigned int* lp3_t;
__device__ __forceinline__ void gload16(const void* g, void* l) {
    // 16B per lane, dest = wave-uniform LDS base + lane*16 (hardware-placed)
    __builtin_amdgcn_global_load_lds((gp1_t)g, (lp3_t)l, 16, 0, 0);
}

// ---------------- fp32 -> bf16 convert with row padding ----------------
__global__ void cvt_pad(const float* __restrict__ s, __hip_bfloat16* __restrict__ d,
                        int rows_real, int K, int total) {
    int i = blockIdx.x * 256 + threadIdx.x;
    if (i >= total) return;
    int row = i / K;
    d[i] = (row < rows_real) ? __float2bfloat16(s[i]) : __float2bfloat16(0.f);
}

// ---------------- LayerNorm over C=320, one wave per token, bf16 out ----------------
__global__ void ln_kernel(const float* __restrict__ x, const float* __restrict__ g,
                          const float* __restrict__ bt, __hip_bfloat16* __restrict__ out) {
    int bn = blockIdx.x;
    int lane = threadIdx.x;
    const float* row = x + (size_t)bn * Cc;
    float v[5];
    float s = 0.f, s2 = 0.f;
    #pragma unroll
    for (int i = 0; i < 5; ++i) {
        v[i] = row[lane + 64 * i];
        s += v[i];
        s2 += v[i] * v[i];
    }
    #pragma unroll
    for (int off = 32; off > 0; off >>= 1) {
        s  += __shfl_down(s, off);
        s2 += __shfl_down(s2, off);
    }
    s  = __shfl(s, 0);
    s2 = __shfl(s2, 0);
    float mean = s * (1.f / 320.f);
    float var  = s2 * (1.f / 320.f) - mean * mean;
    float rstd = rsqrtf(var + 1e-6f);
    __hip_bfloat16* orow = out + (size_t)bn * Cc;
    #pragma unroll
    for (int i = 0; i < 5; ++i) {
        int c = lane + 64 * i;
        orow[c] = __float2bfloat16((v[i] - mean) * rstd * g[c] + bt[c]);
    }
}

// ---------------- bf16 MFMA GEMM, 128x128 tile, BK=64, global_load_lds + XOR swizzle ------
// out = A(MxK) @ W(NpadxK)^T + bias (+res)(+gelu).  NS = out/res row stride, Nreal = guard.
// LDS: As/Bs [128 rows][64 k] linear rows of 128B = 8 slots x 16B; slot ^= (row&7) swizzle
// applied on global SOURCE (staging) and on ds_read (both sides, same involution).
template<int ACT, int RES, int WF32, int WBF16>
__global__ __launch_bounds__(256) void gemm_mfma(
        const __hip_bfloat16* __restrict__ A, const __hip_bfloat16* __restrict__ W,
        const float* __restrict__ bias, const float* __restrict__ res,
        float* __restrict__ outf, __hip_bfloat16* __restrict__ outb,
        int K, int NS, int Nreal) {
    __shared__ __align__(16) short As[128 * 64];
    __shared__ __align__(16) short Bs[128 * 64];
    int tid = threadIdx.x;
    int m0 = blockIdx.x << 7;
    int n0 = blockIdx.y << 7;
    int w = tid >> 6, lane = tid & 63;
    int wr = w >> 1, wc = w & 1;
    int lrow = lane & 15, lk = lane >> 4;
    f4v acc[4][4];
    #pragma unroll
    for (int i = 0; i < 4; ++i)
        #pragma unroll
        for (int j = 0; j < 4; ++j) acc[i][j] = (f4v){0.f, 0.f, 0.f, 0.f};

    // staging geometry: wave w owns rows [w*32, w*32+32) of each tile; 4 issues of 1KB.
    int srow = w * 32 + (lane >> 3);      // row this lane sources (for issue i: +8*i)
    int slot = lane & 7;                  // 16B slot within the 128B row
    for (int k0 = 0; k0 < K; k0 += 64) {
        __syncthreads();                  // prior reads done before overwrite
        #pragma unroll
        for (int i = 0; i < 4; ++i) {
            int row = srow + i * 8;
            int sk = (slot ^ (row & 7)) << 3;     // inverse-swizzled source k-offset
            gload16(&A[(size_t)(m0 + row) * K + k0 + sk], &As[w * 2048 + i * 512]);
            gload16(&W[(size_t)(n0 + row) * K + k0 + sk], &Bs[w * 2048 + i * 512]);
        }
        __syncthreads();                  // compiler drains vmcnt(0) before barrier
        #pragma unroll
        for (int ks = 0; ks < 2; ++ks) {
            s8v af[4], bf[4];
            #pragma unroll
            for (int mi = 0; mi < 4; ++mi) {
                int row = wr * 64 + mi * 16 + lrow;
                int s = (ks * 4 + lk) ^ (row & 7);
                af[mi] = *reinterpret_cast<const s8v*>(&As[row * 64 + s * 8]);
            }
            #pragma unroll
            for (int ni = 0; ni < 4; ++ni) {
                int row = wc * 64 + ni * 16 + lrow;
                int s = (ks * 4 + lk) ^ (row & 7);
                bf[ni] = *reinterpret_cast<const s8v*>(&Bs[row * 64 + s * 8]);
            }
            #pragma unroll
            for (int mi = 0; mi < 4; ++mi)
                #pragma unroll
                for (int ni = 0; ni < 4; ++ni)
                    acc[mi][ni] = __builtin_amdgcn_mfma_f32_16x16x32_bf16(af[mi], bf[ni], acc[mi][ni], 0, 0, 0);
        }
    }
    #pragma unroll
    for (int mi = 0; mi < 4; ++mi) {
        #pragma unroll
        for (int ni = 0; ni < 4; ++ni) {
            int n = n0 + wc * 64 + ni * 16 + lrow;
            if (n >= Nreal) continue;
            float bv = bias[n];
            #pragma unroll
            for (int r = 0; r < 4; ++r) {
                int m = m0 + wr * 64 + mi * 16 + lk * 4 + r;
                float v = acc[mi][ni][r] + bv;
                if (RES) v += res[(size_t)m * NS + n];
                if (ACT == 1) v = 0.5f * v * (1.f + erff(v * 0.70710678118654752f));
                if (WF32) outf[(size_t)m * NS + n] = v;
                if (WBF16) outb[(size_t)m * NS + n] = __float2bfloat16(v);
            }
        }
    }
}

// ---------------- tiled depthwise conv, block = (b, 8ch-group, 16x16 tile) ----------------
template<int KSZ, int EPI, typename ST>
__global__ __launch_bounds__(256) void dwconv_tile(
        const ST* __restrict__ src, int sstride, int scoff,
        const float* __restrict__ wts, const float* __restrict__ bias, int cbase, int ngrp,
        const float* __restrict__ aux0,   // EPI0: residual x ; EPI1: fa
        const float* __restrict__ aux1,   // EPI1: dg
        float* __restrict__ outf, __hip_bfloat16* __restrict__ outb) {
    constexpr int P = KSZ / 2;
    constexpr int S = 16 + 2 * P;
    __shared__ float vt[S * S * 8];
    __shared__ float ws_[8 * KSZ * KSZ];
    int blk = blockIdx.x;
    int tile = blk & 15;
    int g  = (blk >> 4) % ngrp;
    int b  = (blk >> 4) / ngrp;
    int ty0 = (tile >> 2) << 4;
    int tx0 = (tile & 3) << 4;
    int c0 = cbase + g * 8;
    int tid = threadIdx.x;
    for (int e = tid; e < 8 * KSZ * KSZ; e += 256)
        ws_[e] = wts[g * 8 * KSZ * KSZ + e];
    const ST* sb = src + (size_t)b * Nn * sstride + scoff + c0;
    for (int e = tid; e < S * S; e += 256) {
        int hy = e / S, hx = e % S;
        int gy = ty0 - P + hy, gx = tx0 - P + hx;
        float px8[8];
        #pragma unroll
        for (int j = 0; j < 8; ++j) px8[j] = 0.f;
        if ((unsigned)gy < 64u && (unsigned)gx < 64u) {
            const ST* p = &sb[(size_t)((gy << 6) + gx) * sstride];
            if constexpr (std::is_same<ST, float>::value) {
                float4 lo = reinterpret_cast<const float4*>(p)[0];
                float4 hi = reinterpret_cast<const float4*>(p)[1];
                px8[0] = lo.x; px8[1] = lo.y; px8[2] = lo.z; px8[3] = lo.w;
                px8[4] = hi.x; px8[5] = hi.y; px8[6] = hi.z; px8[7] = hi.w;
            } else {
                s8v v8 = *reinterpret_cast<const s8v*>(p);
                #pragma unroll
                for (int j = 0; j < 8; ++j) px8[j] = bf2f(v8[j]);
            }
        }
        #pragma unroll
        for (int j = 0; j < 8; ++j) vt[e * 8 + j] = px8[j];
    }
    __syncthreads();
    int cl  = tid & 7;
    int px  = (tid >> 3) & 15;
    int pyh = tid >> 7;
    int c = c0 + cl;
    float acc[8];
    float bval = bias[g * 8 + cl];
    #pragma unroll
    for (int j = 0; j < 8; ++j) acc[j] = bval;
    #pragma unroll
    for (int dx = 0; dx < KSZ; ++dx) {
        float col[8 + KSZ - 1];
        #pragma unroll
        for (int i = 0; i < 8 + KSZ - 1; ++i)
            col[i] = vt[((pyh * 8 + i) * S + (px + dx)) * 8 + cl];
        #pragma unroll
        for (int j = 0; j < 8; ++j)
            #pragma unroll
            for (int dy = 0; dy < KSZ; ++dy)
                acc[j] += col[j + dy] * ws_[cl * KSZ * KSZ + dy * KSZ + dx];
    }
    #pragma unroll
    for (int j = 0; j < 8; ++j) {
        int n = ((ty0 + pyh * 8 + j) << 6) + tx0 + px;
        size_t bn = (size_t)b * Nn + n;
        if (EPI == 0) {
            outf[bn * Cc + c] = acc[j] + aux0[bn * Cc + c];
        } else {
            float qv  = bf2f(((const short*)src)[bn * (size_t)sstride + c]);
            float fav = aux0[bn * Cc + c];
            float r = aux1[(size_t)b * Cc + c] * (ATT_SCALE * fav + qv * acc[j]);
            outb[bn * Cc + c] = __float2bfloat16(r);
        }
    }
}

// ---------------- kv + softmax-denominator via MFMA ----------------
__global__ __launch_bounds__(256) void kv_mfma(const __hip_bfloat16* __restrict__ qkv,
                                               float* __restrict__ kvp) {
    __shared__ short lds[4 * 2 * 48 * 66];
    int blk = blockIdx.x;
    int s = blk & 7;
    int bh = blk >> 3;
    int h = bh & 7, b = bh >> 3;
    int tid = threadIdx.x;
    int w = tid >> 6, lane = tid & 63;
    short* ke_t = lds + w * 2 * 48 * 66;
    short* vv_t = ke_t + 48 * 66;
    for (int e = lane; e < 8 * 66; e += 64) {
        ke_t[40 * 66 + e] = 0;
        vv_t[40 * 66 + e] = 0;
    }
    for (int n = lane; n < 66; n += 64) vv_t[40 * 66 + n] = (short)0x3F80;

    const short* kb = (const short*)qkv + (size_t)b * Nn * QS + 320 + h * 40;
    const short* vb = kb + 320;
    int col0 = lane & 15, kq = lane >> 4;
    f4v acc[3][3];
    #pragma unroll
    for (int i = 0; i < 3; ++i)
        #pragma unroll
        for (int j = 0; j < 3; ++j) acc[i][j] = (f4v){0.f, 0.f, 0.f, 0.f};

    for (int t = w; t < 8; t += 4) {
        int n0 = s * 512 + t * 64;
        for (int e = lane; e < 320; e += 64) {
            int nl = e / 5, oct = e % 5;
            size_t go = (size_t)(n0 + nl) * QS + oct * 8;
            s8v k8 = *reinterpret_cast<const s8v*>(kb + go);
            s8v v8 = *reinterpret_cast<const s8v*>(vb + go);
            #pragma unroll
            for (int j = 0; j < 8; ++j) {
                ke_t[(oct * 8 + j) * 66 + nl] = f2bf(__expf(bf2f(k8[j])));
                vv_t[(oct * 8 + j) * 66 + nl] = v8[j];
            }
        }
        __syncthreads();
        #pragma unroll
        for (int ks = 0; ks < 2; ++ks) {
            s8v af[3], bfr[3];
            #pragma unroll
            for (int mt = 0; mt < 3; ++mt)
                af[mt] = *reinterpret_cast<const s8v*>(ke_t + (mt * 16 + col0) * 66 + ks * 32 + kq * 8);
            #pragma unroll
            for (int nt = 0; nt < 3; ++nt)
                bfr[nt] = *reinterpret_cast<const s8v*>(vv_t + (nt * 16 + col0) * 66 + ks * 32 + kq * 8);
            #pragma unroll
            for (int mt = 0; mt < 3; ++mt)
                #pragma unroll
                for (int nt = 0; nt < 3; ++nt)
                    acc[mt][nt] = __builtin_amdgcn_mfma_f32_16x16x32_bf16(af[mt], bfr[nt], acc[mt][nt], 0, 0, 0);
        }
        __syncthreads();
    }
    float* red = (float*)lds;
    #pragma unroll
    for (int mt = 0; mt < 3; ++mt) {
        #pragma unroll
        for (int nt = 0; nt < 3; ++nt) {
            #pragma unroll
            for (int r = 0; r < 4; ++r) {
                int ch = mt * 16 + kq * 4 + r;
                int cv = nt * 16 + col0;
                if (ch < 40) red[w * 1920 + ch * 48 + cv] = acc[mt][nt][r];
            }
        }
    }
    __syncthreads();
    for (int p = tid; p < 1920; p += 256) {
        float sv = red[p] + red[1920 + p] + red[2 * 1920 + p] + red[3 * 1920 + p];
        kvp[(size_t)blk * 1920 + p] = sv;
    }
}

__global__ void kv_combine2(const float* __restrict__ kvp, float* __restrict__ kv) {
    int bh = blockIdx.x;
    int tid = threadIdx.x;
    __shared__ float sinv[40];
    if (tid < 40) {
        float S = 0.f;
        for (int s2 = 0; s2 < 8; ++s2)
            S += kvp[(size_t)(bh * 8 + s2) * 1920 + tid * 48 + 40];
        sinv[tid] = 1.f / S;
    }
    __syncthreads();
    for (int p = tid; p < 1600; p += 256) {
        int ch = p / 40, cv = p % 40;
        float v = 0.f;
        for (int s2 = 0; s2 < 8; ++s2)
            v += kvp[(size_t)(bh * 8 + s2) * 1920 + ch * 48 + cv];
        kv[(size_t)bh * 1600 + p] = v * sinv[ch];
    }
}

// ---------------- domain gate ----------------
__global__ void dgate_kernel(const float* __restrict__ lbl, const float* __restrict__ w1,
                             const float* __restrict__ b1, const float* __restrict__ w2,
                             const float* __restrict__ b2, float* __restrict__ dg) {
    int b = blockIdx.x;
    int tid = threadIdx.x;
    __shared__ float hid[160];
    __shared__ float dd[320];
    if (tid < 160) {
        float a = b1[tid];
        for (int d = 0; d < 4; ++d) a += w1[tid * 4 + d] * lbl[b * 4 + d];
        hid[tid] = fmaxf(a, 0.f);
    }
    __syncthreads();
    float a = b2[tid];
    for (int j = 0; j < 160; ++j) a += w2[tid * 160 + j] * hid[j];
    dd[tid] = a;
    __syncthreads();
    if (tid < 40) {
        float M = -1e30f;
        for (int h2 = 0; h2 < 8; ++h2) M = fmaxf(M, dd[h2 * 40 + tid]);
        float S = 0.f;
        float e[8];
        for (int h2 = 0; h2 < 8; ++h2) { e[h2] = __expf(dd[h2 * 40 + tid] - M); S += e[h2]; }
        float inv = 1.f / S;
        for (int h2 = 0; h2 < 8; ++h2) dg[b * 320 + h2 * 40 + tid] = e[h2] * inv;
    }
}

// ---------------- fa = q @ kv, one token per thread ----------------
__global__ __launch_bounds__(256) void fa_kernel(const __hip_bfloat16* __restrict__ qkv,
        const float* __restrict__ kvmat, float* __restrict__ fa) {
    __shared__ float kvs[1600];
    int blk = blockIdx.x;
    int chunk = blk & 15;
    int bh = blk >> 4;
    int h = bh & 7, b = bh >> 3;
    int tid = threadIdx.x;
    for (int e = tid; e < 1600; e += 256) kvs[e] = kvmat[(size_t)bh * 1600 + e];
    __syncthreads();
    int n = chunk * 256 + tid;
    const short* qr = (const short*)qkv + (size_t)(b * Nn + n) * QS + h * 40;
    float q[40];
    #pragma unroll
    for (int i = 0; i < 5; ++i) {
        s8v v8 = reinterpret_cast<const s8v*>(qr)[i];
        #pragma unroll
        for (int j = 0; j < 8; ++j) q[i * 8 + j] = bf2f(v8[j]);
    }
    float o[40];
    #pragma unroll
    for (int cv = 0; cv < 40; ++cv) o[cv] = 0.f;
    #pragma unroll
    for (int ch = 0; ch < 40; ++ch) {
        float qv = q[ch];
        #pragma unroll
        for (int cv = 0; cv < 40; ++cv)
            o[cv] += qv * kvs[ch * 40 + cv];
    }
    float* fr = fa + (size_t)(b * Nn + n) * 320 + h * 40;
    #pragma unroll
    for (int i = 0; i < 10; ++i)
        reinterpret_cast<float4*>(fr)[i] = make_float4(o[i * 4], o[i * 4 + 1], o[i * 4 + 2], o[i * 4 + 3]);
}

extern "C" void kernel_launch(void* const* d_in, const int* in_sizes, int n_in,
                              void* d_out, int out_size, void* d_ws, size_t ws_size,
                              hipStream_t stream) {
    const float* x     = (const float*)d_in[0];
    const float* lbl   = (const float*)d_in[1];
    const float* cpe_w = (const float*)d_in[2];
    const float* cpe_b = (const float*)d_in[3];
    const float* ln1g  = (const float*)d_in[4];
    const float* ln1b  = (const float*)d_in[5];
    const float* qkv_w = (const float*)d_in[6];
    const float* qkv_b = (const float*)d_in[7];
    const float* w3    = (const float*)d_in[8];
    const float* b3    = (const float*)d_in[9];
    const float* w5    = (const float*)d_in[10];
    const float* b5    = (const float*)d_in[11];
    const float* w7    = (const float*)d_in[12];
    const float* b7    = (const float*)d_in[13];
    const float* dw1   = (const float*)d_in[14];
    const float* db1   = (const float*)d_in[15];
    const float* dw2   = (const float*)d_in[16];
    const float* db2   = (const float*)d_in[17];
    const float* pw    = (const float*)d_in[18];
    const float* pb    = (const float*)d_in[19];
    const float* ln2g  = (const float*)d_in[20];
    const float* ln2b  = (const float*)d_in[21];
    const float* m1w   = (const float*)d_in[22];
    const float* m1b   = (const float*)d_in[23];
    const float* m2w   = (const float*)d_in[24];
    const float* m2b   = (const float*)d_in[25];
    float* out = (float*)d_out;

    // ws floats total ~55.3M = 221 MB
    float* ws = (float*)d_ws;
    float* x1   = ws; ws += 10485760;                            // (B,N,C) fp32
    __hip_bfloat16* qkvb = (__hip_bfloat16*)ws; ws += 16777216;  // (B,N,QS=1024) bf16
    float* fa   = ws; ws += 20971520;                            // fa fp32 / gelu bf16 union
    __hip_bfloat16* gelub = (__hip_bfloat16*)fa;
    __hip_bfloat16* bb1   = (__hip_bfloat16*)ws; ws += 5242880;  // (B,N,C) bf16
    __hip_bfloat16* wb    = (__hip_bfloat16*)ws; ws += 675840;   // padded bf16 weights
    float* kvp  = ws; ws += 983040;
    float* kv   = ws; ws += 102400;
    float* dg   = ws; ws += 2560;
    __hip_bfloat16* wbq  = wb;                      // 1024 x 320
    __hip_bfloat16* wbp  = wbq  + 1024 * 320;       //  384 x 320
    __hip_bfloat16* wbm1 = wbp  + 384 * 320;        // 1280 x 320
    __hip_bfloat16* wbm2 = wbm1 + 1280 * 320;       //  384 x 1280

    // 0. weights -> bf16 (zero-padded rows)
    cvt_pad<<<1280, 256, 0, stream>>>(qkv_w, wbq,  960, 320, 1024 * 320);
    cvt_pad<<<480,  256, 0, stream>>>(pw,    wbp,  320, 320, 384 * 320);
    cvt_pad<<<1600, 256, 0, stream>>>(m1w,   wbm1, 1280, 320, 1280 * 320);
    cvt_pad<<<1920, 256, 0, stream>>>(m2w,   wbm2, 320, 1280, 384 * 1280);
    // 1. CPE conv + residual -> x1 (fp32)
    dwconv_tile<3, 0, float><<<B_ * 40 * 16, 256, 0, stream>>>(
        x, 320, 0, cpe_w, cpe_b, 0, 40, x, nullptr, x1, nullptr);
    // 2. LN1 -> bb1 (bf16)
    ln_kernel<<<B_ * Nn, 64, 0, stream>>>(x1, ln1g, ln1b, bb1);
    // 3. QKV GEMM -> qkvb (bf16, stride 1024, cols 960..1023 unwritten)
    {
        dim3 g(256, 8);
        gemm_mfma<0, 0, 0, 1><<<g, 256, 0, stream>>>(bb1, wbq, qkv_b, nullptr, nullptr, qkvb,
                                                     320, QS, 960);
    }
    // 4. kv (+ softmax denominator) via MFMA
    kv_mfma<<<512, 256, 0, stream>>>(qkvb, kvp);
    kv_combine2<<<64, 256, 0, stream>>>(kvp, kv);
    // 5. domain gate
    dgate_kernel<<<B_, 320, 0, stream>>>(lbl, dw1, db1, dw2, db2, dg);
    // 6. fa = q @ kv
    fa_kernel<<<B_ * 8 * 16, 256, 0, stream>>>(qkvb, kv, fa);
    // 7. crpe conv + combine -> bb1 (bf16 att)
    dwconv_tile<3, 1, __hip_bfloat16><<<B_ * 10 * 16, 256, 0, stream>>>(
        qkvb, QS, 640, w3, b3, 0, 10, fa, dg, nullptr, bb1);
    dwconv_tile<5, 1, __hip_bfloat16><<<B_ * 15 * 16, 256, 0, stream>>>(
        qkvb, QS, 640, w5, b5, 80, 15, fa, dg, nullptr, bb1);
    dwconv_tile<7, 1, __hip_bfloat16><<<B_ * 15 * 16, 256, 0, stream>>>(
        qkvb, QS, 640, w7, b7, 200, 15, fa, dg, nullptr, bb1);
    // 8. proj GEMM + residual(x1) -> d_out
    {
        dim3 g(256, 3);
        gemm_mfma<0, 1, 1, 0><<<g, 256, 0, stream>>>(bb1, wbp, pb, x1, out, nullptr,
                                                     320, 320, 320);
    }
    // 9. LN2 -> bb1
    ln_kernel<<<B_ * Nn, 64, 0, stream>>>(out, ln2g, ln2b, bb1);
    // 10. MLP1 + GELU -> gelub (bf16)
    {
        dim3 g(256, 10);
        gemm_mfma<1, 0, 0, 1><<<g, 256, 0, stream>>>(bb1, wbm1, m1b, nullptr, nullptr, gelub,
                                                     320, 1280, 1280);
    }
    // 11. MLP2 + residual(d_out) -> d_out
    {
        dim3 g(256, 3);
        gemm_mfma<0, 1, 1, 0><<<g, 256, 0, stream>>>(gelub, wbm2, m2b, out, out, nullptr,
                                                     1280, 320, 320);
    }
}